// Round 8
// baseline (2065.951 us; speedup 1.0000x reference)
//
#include <hip/hip_runtime.h>

// Problem dims (fixed by setup_inputs)
constexpr int NB = 1024;   // batch
constexpr int NT = 512;    // time steps
constexpr int NI = 100;    // input dim
constexpr int NH = 150;    // hidden dim
constexpr int NO = 3;      // output classes

// DPP-based add: v += shuffled(v).
// 0xB1 quad_perm xor1 | 0x4E quad_perm xor2 | 0x141 row_half_mirror (completes 8-sum)
// 0x140 row_mirror (completes 16-sum)
template<int CTRL>
__device__ __forceinline__ float dpp_add(float v) {
    int t = __builtin_amdgcn_update_dpp(0, __float_as_int(v), CTRL, 0xF, 0xF, true);
    return v + __int_as_float(t);
}

// Async global->LDS copy, 4B per lane: LDS dest = uniform base + lane*4.
__device__ __forceinline__ void async_copy_f32(const float* src, float* lds_dst) {
    __builtin_amdgcn_global_load_lds(
        (const __attribute__((address_space(1))) void*)src,
        (__attribute__((address_space(3))) void*)lds_dst, 4, 0, 0);
}

// ============ Kernel 1: xw[t][b][h] = sum_i x[b,t,i] * Wih[h,i]  (packed [T][B][150])
// PERSISTENT: grid = 256 blocks x 512 thr. Each block stages Wih into LDS ONCE
// (60.8 KB), then loops over its 32 tiles (64 b-rows x 1 t each), double-buffering
// the x tile (global->regs during compute, regs->LDS after the barrier).
// Within a wave: row = lane (64 rows), h-group = wave id (19 h each) -> W reads are
// wave-uniform ds_read_b128 (broadcast, conflict-free); x reads stride-101 (2-way, free).
// Output staged in LDS (stride 153) -> coalesced float2 stores.
constexpr int XR = 64, XTH = 512, NTILES = (NB / XR) * NT, XBLK = 256;
__global__ __launch_bounds__(XTH, 1)
void xw_gemm(const float* __restrict__ x, const float* __restrict__ Wih,
             float* __restrict__ xw)
{
    __shared__ __align__(16) float Wl[152 * NI];    // 60.8 KB
    __shared__ float xT[2][XR * 101];               // 51.7 KB
    __shared__ float ot[XR * 153];                  // 39.2 KB
    const int tid = threadIdx.x;

    // ---- stage W once (rows 150,151 zero) ----
    for (int e = tid; e < 152 * 25; e += XTH) {
        int wr = e / 25, k4 = e - wr * 25;
        float4 v = make_float4(0.f, 0.f, 0.f, 0.f);
        if (wr < NH) v = *reinterpret_cast<const float4*>(Wih + (size_t)wr * NI + 4 * k4);
        *reinterpret_cast<float4*>(&Wl[wr * NI + 4 * k4]) = v;
    }

    const int row = tid & 63;           // lane = row within a wave
    const int hg  = tid >> 6;           // wave id = h-group (19 h each)
    const int tile0 = blockIdx.x * (NTILES / XBLK);   // 32 tiles per block

    // tile id -> (t, b0):  id = t * 16 + btile
    auto tile_t = [](int id) { return id >> 4; };
    auto tile_b = [](int id) { return (id & 15) * XR; };

    // ---- prologue: stage tile0 into xT[0] ----
    {
        const int t = tile_t(tile0), b0 = tile_b(tile0);
        for (int e = tid; e < XR * 25; e += XTH) {
            int r = e / 25, k4 = e - r * 25;
            float4 v = *reinterpret_cast<const float4*>(
                x + ((size_t)(b0 + r) * NT + t) * NI + 4 * k4);
            float* d = &xT[0][r * 101 + 4 * k4];
            d[0] = v.x; d[1] = v.y; d[2] = v.z; d[3] = v.w;
        }
    }
    __syncthreads();

    int cur = 0;
    for (int it = 0; it < NTILES / XBLK; ++it) {
        const int id = tile0 + it;
        const int t = tile_t(id), b0 = tile_b(id);

        // A: load next tile's x into regs (hides HBM latency under compute)
        float4 pre[4];
        int preN = 0;
        if (it + 1 < NTILES / XBLK) {
            const int t2 = tile_t(id + 1), b2 = tile_b(id + 1);
            for (int e = tid; e < XR * 25; e += XTH) {
                int r = e / 25, k4 = e - r * 25;
                pre[preN++] = *reinterpret_cast<const float4*>(
                    x + ((size_t)(b2 + r) * NT + t2) * NI + 4 * k4);
            }
        }

        // B: compute 19 h-outputs for this thread's row
        float acc[19];
#pragma unroll
        for (int j = 0; j < 19; ++j) acc[j] = 0.f;
        const float* xr = &xT[cur][row * 101];
        const float* wb = &Wl[19 * hg * NI];
        for (int k4 = 0; k4 < 25; ++k4) {
            const float x0 = xr[4 * k4 + 0], x1 = xr[4 * k4 + 1];
            const float x2 = xr[4 * k4 + 2], x3 = xr[4 * k4 + 3];
#pragma unroll
            for (int j = 0; j < 19; ++j) {
                const float4 w4 = *reinterpret_cast<const float4*>(&wb[j * NI + 4 * k4]);
                acc[j] += w4.x * x0; acc[j] += w4.y * x1;
                acc[j] += w4.z * x2; acc[j] += w4.w * x3;
            }
        }

        __syncthreads();   // xT[cur] fully read; ot free (stores of prev tile done)

        // D: write acc -> ot; write prefetched x -> xT[cur^1]
#pragma unroll
        for (int j = 0; j < 19; ++j) {
            const int h = 19 * hg + j;
            if (h < NH) ot[row * 153 + h] = acc[j];
        }
        if (it + 1 < NTILES / XBLK) {
            int n = 0;
            for (int e = tid; e < XR * 25; e += XTH) {
                int r = e / 25, k4 = e - r * 25;
                float* d = &xT[cur ^ 1][r * 101 + 4 * k4];
                float4 v = pre[n++];
                d[0] = v.x; d[1] = v.y; d[2] = v.z; d[3] = v.w;
            }
        }
        __syncthreads();   // ot ready, next xT ready

        // F: coalesced float2 stores of the 64x150 tile
        for (int e = tid; e < XR * 75; e += XTH) {
            int r = e / 75, c2 = e - r * 75;
            float2 v = make_float2(ot[r * 153 + 2 * c2], ot[r * 153 + 2 * c2 + 1]);
            *reinterpret_cast<float2*>(&xw[((size_t)t * NB + b0 + r) * NH + 2 * c2]) = v;
        }
        cur ^= 1;
    }
}

// ============ Kernel 2: recurrence h_t = relu(xw_t + h_{t-1} Whh^T), fc, gumbel-emit
// 256 thr = 4 waves, ROWS=1, grid 1024 = 4 blocks/CU (independent barriers overlap).
// kg = lane&7 (8 k-groups x 5 f4-chunks of K=160); oi = wv*8 + (lane>>3) in [0,32);
// o-slots o = oi+32j, j<5 (o<150 h-rows, 150..152 fc, rest dead W=0).
// launch_bounds(256,2): give the allocator >=128 arch VGPRs so Wreg (100 floats)
// stays in arch regs (R7's (256,4) forced the 64-cap -> W in the AGPR half).
// 3-stage DPP reduce. xw[t+1] prefetched via global_load_lds (0 VGPR cost).
constexpr int RTH = 256;
__global__ __launch_bounds__(RTH, 2)
void rnn_rec(const float* __restrict__ xw, const float* __restrict__ h0v,
             const float* __restrict__ g, const float* __restrict__ Whh,
             const float* __restrict__ Wfc, float* __restrict__ out,
             float* __restrict__ hidden, float* __restrict__ logits)
{
    __shared__ __align__(16) float hx[2][160];   // h + 10 zero-pad, double-buffered
    __shared__ __align__(16) float xq[2][152];   // xw stream double-buffer
    __shared__ float lg[2][4];

    const int tid = threadIdx.x, lane = tid & 63, wv = tid >> 6;
    const int kg = lane & 7, oq = lane >> 3;
    const int oi = wv * 8 + oq;        // 0..31
    const int row = blockIdx.x;

    // W slice: 5 o-slots x 5 chunks x 4 = 100 regs
    float Wreg[5][5][4];
#pragma unroll
    for (int j = 0; j < 5; ++j) {
        const int o = oi + 32 * j;
#pragma unroll
        for (int i = 0; i < 5; ++i)
#pragma unroll
            for (int q = 0; q < 4; ++q) {
                const int k = 4 * (kg + 8 * i) + q;
                float v = 0.f;
                if (k < NH) {
                    if (o < NH) v = Whh[o * NH + k];
                    else if (o < NH + NO) v = Wfc[(o - NH) * NH + k];
                }
                Wreg[j][i][q] = v;
            }
    }

    if (tid < NH) hx[0][tid] = h0v[(size_t)row * NH + tid];
    if (tid < 20) { int f = tid / 10, z = tid - 10 * (tid / 10); hx[f][NH + z] = 0.f; }
    {   // prologue: xw[0] -> xq[0]
        const float* s = xw + (size_t)row * NH;
        if (tid < 64) { async_copy_f32(s + tid, &xq[0][0]); async_copy_f32(s + 64 + tid, &xq[0][64]); }
        if (tid < 22) async_copy_f32(s + 128 + tid, &xq[0][128]);
    }
    __syncthreads();

    float* hidb = hidden + (size_t)row * NT * NH;
    const float* gb = g + (size_t)row * NT * NO;
    float* ob = out + (size_t)row * NT * NO;
    float* lb = logits + (size_t)row * NT * NO;

    auto stepf = [&](int t, const float* __restrict__ cur, float* __restrict__ nxt,
                     float* __restrict__ lgc, const float* __restrict__ xv,
                     float* __restrict__ xnxt) {
        // issue async prefetch of xw[t+1] (full step of slack before barrier drain)
        if (t + 1 < NT) {
            const float* s = xw + ((size_t)(t + 1) * NB + row) * NH;
            if (tid < 64) { async_copy_f32(s + tid, xnxt); async_copy_f32(s + 64 + tid, xnxt + 64); }
            if (tid < 22) async_copy_f32(s + 128 + tid, xnxt + 128);
        }
        // partial dots over this thread's 5 chunks
        float acc[5];
#pragma unroll
        for (int j = 0; j < 5; ++j) acc[j] = 0.f;
        const float4* c4 = reinterpret_cast<const float4*>(cur);
#pragma unroll
        for (int i = 0; i < 5; ++i) {
            const float4 hv = c4[kg + 8 * i];   // 8 distinct addrs, broadcast to oq: conflict-free
#pragma unroll
            for (int j = 0; j < 5; ++j) {
                acc[j] += Wreg[j][i][0] * hv.x; acc[j] += Wreg[j][i][1] * hv.y;
                acc[j] += Wreg[j][i][2] * hv.z; acc[j] += Wreg[j][i][3] * hv.w;
            }
        }
        // 3-stage DPP butterfly across the 8 k-groups
#pragma unroll
        for (int j = 0; j < 5; ++j) {
            float v = acc[j];
            v = dpp_add<0xB1>(v); v = dpp_add<0x4E>(v); v = dpp_add<0x141>(v);
            acc[j] = v;
        }
        // phase B: kg==0 lanes write their 5 o-slots
        if (kg == 0) {
#pragma unroll
            for (int j = 0; j < 5; ++j) {
                const int o = oi + 32 * j;
                if (o < NH) {
                    if (t < NT) {
                        float v = fmaxf(acc[j] + xv[o], 0.f);
                        nxt[o] = v;
                        hidb[(size_t)t * NH + o] = v;
                    }
                } else if (o < NH + NO) lgc[o - NH] = acc[j];
            }
        }
        __syncthreads();   // drains prefetch (vmcnt) + hx/lg writes
        // emit out/logits for time t-1
        if (tid == 0 && t >= 1) {
            float l0 = lgc[0], l1 = lgc[1], l2 = lgc[2];
            const float* gp = gb + (size_t)(t - 1) * NO;
            float s0 = l0 + gp[0], s1 = l1 + gp[1], s2 = l2 + gp[2];
            int am = 0; float best = s0;
            if (s1 > best) { best = s1; am = 1; }
            if (s2 > best) am = 2;
            size_t base = (size_t)(t - 1) * NO;
            ob[base + 0] = (am == 0) ? 1.f : 0.f;
            ob[base + 1] = (am == 1) ? 1.f : 0.f;
            ob[base + 2] = (am == 2) ? 1.f : 0.f;
            lb[base + 0] = l0; lb[base + 1] = l1; lb[base + 2] = l2;
        }
    };

    for (int t = 0; t < NT; t += 2) {
        stepf(t,     hx[0], hx[1], lg[0], xq[0], xq[1]);
        stepf(t + 1, hx[1], hx[0], lg[1], xq[1], xq[0]);
    }
    stepf(NT, hx[0], hx[1], lg[0], xq[0], xq[1]);  // tail: fc of h[NT-1] + final emit
}

// ============ Fallback (R5 fused kernel verbatim) if d_ws is too small ============
namespace fb {
constexpr int KP = 256, XOFF = 152, ROWS = 2, KG = 16, NCH = 4, NJ = 5, NTH = 512;
__global__ __launch_bounds__(NTH, 2)
void rnn_fused(const float* __restrict__ x, const float* __restrict__ h0,
               const float* __restrict__ g, const float* __restrict__ Wih,
               const float* __restrict__ Whh, const float* __restrict__ Wfc,
               float* __restrict__ out, float* __restrict__ hidden,
               float* __restrict__ logits)
{
    __shared__ __align__(16) float hx[2][ROWS * KP];
    __shared__ float lg[2][ROWS][4];
    const int tid = threadIdx.x, lane = tid & 63, wv = tid >> 6;
    const int kg = lane & 15, oq = lane >> 4, oi = wv * 4 + oq;
    const int row0 = blockIdx.x * ROWS;
    float Wreg[NJ][NCH][4];
#pragma unroll
    for (int j = 0; j < NJ; ++j) {
        const int o = oi + 32 * j;
#pragma unroll
        for (int i = 0; i < NCH; ++i)
#pragma unroll
            for (int q = 0; q < 4; ++q) {
                const int k = 4 * (kg + KG * i) + q;
                float v = 0.f;
                if (o < NH) {
                    if (k < NH) v = Whh[o * NH + k];
                    else if (k >= XOFF && k < XOFF + NI) v = Wih[o * NI + (k - XOFF)];
                } else if (o < NH + NO) {
                    if (k < NH) v = Wfc[(o - NH) * NH + k];
                }
                Wreg[j][i][q] = v;
            }
    }
    for (int e = tid; e < ROWS * NH; e += NTH) {
        int b = e / NH, k = e - b * NH;
        hx[0][b * KP + k] = h0[(row0 + b) * NH + k];
    }
    for (int e = tid; e < ROWS * NI; e += NTH) {
        int b = e / NI, i = e - b * NI;
        hx[0][b * KP + XOFF + i] = x[((size_t)(row0 + b) * NT + 0) * NI + i];
    }
    if (tid < 2 * ROWS * 6) {
        int u = tid; int f = u / (ROWS * 6); u -= f * (ROWS * 6);
        int b = u / 6, z = u - b * 6;
        int k = (z < 2) ? (NH + z) : (252 + z - 2);
        hx[f][b * KP + k] = 0.f;
    }
    __syncthreads();
    const int xb = (tid / 25) & 1, xq = tid - (tid / 25) * 25;
    const float* xrow = x + ((size_t)(row0 + xb) * NT) * NI + 4 * xq;
    float* hidb = hidden + ((size_t)(row0 + (kg & 1)) * NT) * NH;
    const float* grow = g + ((size_t)(row0 + (tid & 1)) * NT) * NO;
    const size_t emitb = ((size_t)(row0 + (tid & 1)) * NT) * NO;
    auto stepf = [&](int t, const float* __restrict__ cur, float* __restrict__ nxt,
                     float (*__restrict__ lgb)[4]) {
        float4 xp = make_float4(0.f, 0.f, 0.f, 0.f);
        const bool do_x = (tid < 50) && (t < NT - 1);
        if (do_x) xp = *reinterpret_cast<const float4*>(xrow + (size_t)(t + 1) * NI);
        float g0 = 0.f, g1 = 0.f, g2 = 0.f;
        const bool do_e = (tid < ROWS) && (t >= 1);
        if (do_e) {
            const float* gp = grow + (size_t)(t - 1) * NO;
            g0 = gp[0]; g1 = gp[1]; g2 = gp[2];
        }
        const float4* cur4 = reinterpret_cast<const float4*>(cur) + kg;
        float acc[NJ][ROWS];
#pragma unroll
        for (int j = 0; j < NJ; ++j)
#pragma unroll
            for (int b = 0; b < ROWS; ++b) acc[j][b] = 0.f;
#pragma unroll
        for (int i = 0; i < NCH; ++i)
#pragma unroll
            for (int b = 0; b < ROWS; ++b) {
                const float4 hv = cur4[b * (KP / 4) + KG * i];
#pragma unroll
                for (int j = 0; j < NJ; ++j) {
                    acc[j][b] += Wreg[j][i][0] * hv.x;
                    acc[j][b] += Wreg[j][i][1] * hv.y;
                    acc[j][b] += Wreg[j][i][2] * hv.z;
                    acc[j][b] += Wreg[j][i][3] * hv.w;
                }
            }
#pragma unroll
        for (int j = 0; j < NJ; ++j)
#pragma unroll
            for (int b = 0; b < ROWS; ++b) {
                float v = acc[j][b];
                v = dpp_add<0xB1>(v); v = dpp_add<0x4E>(v);
                v = dpp_add<0x141>(v); v = dpp_add<0x140>(v);
                acc[j][b] = v;
            }
        if (kg < ROWS) {
            const int b = kg;
#pragma unroll
            for (int j = 0; j < NJ; ++j) {
                const int o = oi + 32 * j;
                if (o < NH) {
                    if (t < NT) {
                        float v = fmaxf(acc[j][b], 0.f);
                        nxt[b * KP + o] = v;
                        hidb[(size_t)t * NH + o] = v;
                    }
                } else if (o < NH + NO) {
                    lgb[b][o - NH] = acc[j][b];
                }
            }
        }
        if (do_x) *reinterpret_cast<float4*>(nxt + xb * KP + XOFF + 4 * xq) = xp;
        __syncthreads();
        if (do_e) {
            float l0 = lgb[tid][0], l1 = lgb[tid][1], l2 = lgb[tid][2];
            float s0 = l0 + g0, s1 = l1 + g1, s2 = l2 + g2;
            int am = 0; float best = s0;
            if (s1 > best) { best = s1; am = 1; }
            if (s2 > best) { am = 2; }
            size_t base = emitb + (size_t)(t - 1) * NO;
            out[base + 0] = (am == 0) ? 1.f : 0.f;
            out[base + 1] = (am == 1) ? 1.f : 0.f;
            out[base + 2] = (am == 2) ? 1.f : 0.f;
            logits[base + 0] = l0;
            logits[base + 1] = l1;
            logits[base + 2] = l2;
        }
    };
    for (int t = 0; t < NT; t += 2) {
        stepf(t,     hx[0], hx[1], lg[0]);
        stepf(t + 1, hx[1], hx[0], lg[1]);
    }
    stepf(NT, hx[0], hx[1], lg[0]);
}
}  // namespace fb

extern "C" void kernel_launch(void* const* d_in, const int* in_sizes, int n_in,
                              void* d_out, int out_size, void* d_ws, size_t ws_size,
                              hipStream_t stream) {
    const float* x   = (const float*)d_in[0];
    const float* h0  = (const float*)d_in[1];
    const float* g   = (const float*)d_in[2];
    const float* Wih = (const float*)d_in[3];
    const float* Whh = (const float*)d_in[4];
    const float* Wfc = (const float*)d_in[5];

    float* out    = (float*)d_out;
    float* hidden = out + (size_t)NB * NT * NO;
    float* logits = hidden + (size_t)NB * NT * NH;

    const size_t need = (size_t)NT * NB * NH * sizeof(float);  // 314.6 MB (R6-proven)
    if (d_ws != nullptr && ws_size >= need) {
        float* xwbuf = (float*)d_ws;
        hipLaunchKernelGGL(xw_gemm, dim3(XBLK), dim3(XTH), 0, stream,
                           x, Wih, xwbuf);
        hipLaunchKernelGGL(rnn_rec, dim3(NB), dim3(RTH), 0, stream,
                           xwbuf, h0, g, Whh, Wfc, out, hidden, logits);
    } else {
        hipLaunchKernelGGL(fb::rnn_fused, dim3(NB / fb::ROWS), dim3(fb::NTH), 0, stream,
                           x, h0, g, Wih, Whh, Wfc, out, hidden, logits);
    }
}